// Round 2
// baseline (26.533 us; speedup 1.0000x reference)
//
#include <hip/hip_runtime.h>

#define NRES   23
#define NA37   37
#define NSC    34
#define DIM    128
#define RAD2   64.0f

// One fused kernel. Block (b,i) with 128 threads (one per embedding dim d).
// Stage per-residue meta for batch b in LDS (thread t handles residue t):
//   CA pos * mask, |CA|^2, mask, argmax restype.
// Then each thread walks j=0..L-1; the d2<RAD2 test is block-uniform
// (computed from LDS values identical across lanes), and for the ~2-6
// neighbors we compute S_j[d] = sum_a vm*(re[j,d]+vm*ae[a+3,d]) on demand
// (34 FMAs). Epilogue subtracts the self atom term (diagonal removal) and
// applies the vm>0 gate.
__global__ void k_fused(const float* __restrict__ aa,   // (BL,23)
                        const float* __restrict__ re,   // (BL,128)
                        const float* __restrict__ bb,   // (BL,4,3)
                        const float* __restrict__ mask, // (BL,)
                        const float* __restrict__ tbl,  // (23,37)
                        const float* __restrict__ ae,   // (37,128)
                        float* __restrict__ out,        // (BL,34,128)
                        int L)
{
    int bi = blockIdx.x;
    int b  = bi / L;
    int i  = bi % L;
    int t  = threadIdx.x;

    __shared__ float cx[128], cy[128], cz[128], cs[128], mm[128];
    __shared__ int   rts[128];

    // ---- stage residue t of batch b (L == blockDim.x == 128) ----
    {
        int gj = b * L + t;
        float m = mask[gj];
        const float* bbr = bb + (size_t)gj * 12 + 3;   // atom 1 = CA
        float x = bbr[0] * m, y = bbr[1] * m, z = bbr[2] * m;
        cx[t] = x; cy[t] = y; cz[t] = z;
        cs[t] = x * x + y * y + z * z;
        mm[t] = m;

        // argmax over aa_pred[gj, 0:20] (cols 20..22 are forced to -1e9 in
        // the reference and can never win against finite normals).
        const float* aarow = aa + (size_t)gj * NRES;
        int rt = 0; float best = aarow[0];
#pragma unroll
        for (int k = 1; k < 20; ++k) {
            float v = aarow[k];
            if (v > best) { best = v; rt = k; }
        }
        rts[t] = rt;
    }
    __syncthreads();

    int d = t;
    float xi = cx[i], yi = cy[i], zi = cz[i], si = cs[i];

    const float* reb = re + ((size_t)b * L) * DIM + d;

    float r = 0.f;
    for (int j = 0; j < L; ++j) {
        // identical algebra to the reference: sq_i + sq_j - 2*dot
        float d2 = si + cs[j] - 2.f * (xi * cx[j] + yi * cy[j] + zi * cz[j]);
        if (d2 < RAD2) {                      // block-uniform branch
            const float* trow = tbl + rts[j] * NA37 + 3;
            float mj  = mm[j];
            float rej = reb[(size_t)j * DIM];
            float s = 0.f;
#pragma unroll
            for (int a = 0; a < NSC; ++a) {
                float vm = trow[a] * mj;
                s += vm * (rej + vm * ae[(a + 3) * DIM + d]);
            }
            r += s;
        }
    }

    // ---- epilogue: out[(i,a),d] = vm>0 ? r - sc_emb(i,a,d) : 0 ----
    float m_i = mm[i];
    const float* trowi = tbl + rts[i] * NA37 + 3;
    float red = reb[(size_t)i * DIM];
    float* orow = out + (size_t)bi * NSC * DIM + d;
#pragma unroll
    for (int a = 0; a < NSC; ++a) {
        float vm = trowi[a] * m_i;
        float sc = vm * (red + vm * ae[(a + 3) * DIM + d]);
        orow[(size_t)a * DIM] = (vm > 0.f) ? (r - sc) : 0.f;
    }
}

extern "C" void kernel_launch(void* const* d_in, const int* in_sizes, int n_in,
                              void* d_out, int out_size, void* d_ws, size_t ws_size,
                              hipStream_t stream) {
    const float* aa   = (const float*)d_in[0];  // aa_pred (B,L,23)
    const float* re   = (const float*)d_in[1];  // residue_embeddings (B,L,128)
    const float* bb   = (const float*)d_in[2];  // bb_pred (B,L,4,3)
    const float* mask = (const float*)d_in[3];  // mask (B,L)
    const float* tbl  = (const float*)d_in[4];  // valid_atom37_mask (23,37)
    const float* ae   = (const float*)d_in[5];  // atom_embed (37,128)
    float* out = (float*)d_out;

    const int BL = in_sizes[3];  // B*L
    const int L  = 128;          // per reference setup

    k_fused<<<BL, DIM, 0, stream>>>(aa, re, bb, mask, tbl, ae, out, L);
}

// Round 3
// 14.488 us; speedup vs baseline: 1.8313x; 1.8313x over previous
//
#include <hip/hip_runtime.h>

#define NRES 23
#define NA37 37
#define NSC  34
#define DIM  128
#define RAD2 64.0f

// One fused kernel, one dispatch. Block (b,i), 128 threads (one per dim d).
// Phase 1: thread t stages residue t's meta (CA*mask, |CA|^2, mask, argmax
//          restype) into LDS.
// Phase 2: thread t computes d2(i,t) -> __ballot -> 2x64-bit neighbor mask
//          (parallel adjacency, replaces the 128-iteration serial scan).
// Phase 3: iterate the ~2-6 set bits; per neighbor j accumulate
//          S_j[d] = sum_a vm*(re[j,d] + vm*ae[a+3,d])  (34 FMAs, L1-hot).
// Phase 4: out[(i,a),d] = vm_i[a]>0 ? r - sc_emb(i,a,d) : 0  (diagonal
//          removal == self-term subtraction since d2(i,i)=0 is in the mask).
__global__ __launch_bounds__(128) void k_fused(
        const float* __restrict__ aa,   // (BL,23)
        const float* __restrict__ re,   // (BL,128)
        const float* __restrict__ bb,   // (BL,4,3)
        const float* __restrict__ mask, // (BL,)
        const float* __restrict__ tbl,  // (23,37)
        const float* __restrict__ ae,   // (37,128)
        float* __restrict__ out)        // (BL,34,128)
{
    int bi = blockIdx.x;
    int b  = bi >> 7;      // L = 128
    int i  = bi & 127;
    int t  = threadIdx.x;

    __shared__ float cx[128], cy[128], cz[128], cs[128], mm[128];
    __shared__ int   rts[128];
    __shared__ unsigned long long nbm[2];

    // ---- phase 1: stage residue t of batch b ----
    {
        int gj = (b << 7) + t;
        float m = mask[gj];
        const float* bbr = bb + (size_t)gj * 12 + 3;   // atom 1 = CA
        float x = bbr[0] * m, y = bbr[1] * m, z = bbr[2] * m;
        cx[t] = x; cy[t] = y; cz[t] = z;
        cs[t] = x * x + y * y + z * z;
        mm[t] = m;

        // argmax over aa_pred[gj, 0:20]; cols 20..22 are -1e9 in the
        // reference and can never win against finite normals.
        const float* aarow = aa + (size_t)gj * NRES;
        int rt = 0; float best = aarow[0];
#pragma unroll
        for (int k = 1; k < 20; ++k) {
            float v = aarow[k];
            if (v > best) { best = v; rt = k; }
        }
        rts[t] = rt;
    }
    __syncthreads();

    // ---- phase 2: parallel adjacency ballot (thread t tests j = t) ----
    {
        float d2 = cs[i] + cs[t]
                 - 2.f * (cx[i] * cx[t] + cy[i] * cy[t] + cz[i] * cz[t]);
        unsigned long long bal = __ballot(d2 < RAD2);
        if ((t & 63) == 0) nbm[t >> 6] = bal;
    }
    __syncthreads();

    // ---- phase 3: accumulate over neighbors ----
    int d = t;
    const float* reb = re + ((size_t)b << 7) * DIM + d;
    float r = 0.f;
    unsigned long long m0 = nbm[0], m1 = nbm[1];
    while (m0) {
        int j = __builtin_ctzll(m0); m0 &= m0 - 1;
        const float* trow = tbl + rts[j] * NA37 + 3;
        float mj  = mm[j];
        float rej = reb[(size_t)j * DIM];
        float s = 0.f;
#pragma unroll
        for (int a = 0; a < NSC; ++a) {
            float vm = trow[a] * mj;
            s += vm * (rej + vm * ae[(a + 3) * DIM + d]);
        }
        r += s;
    }
    while (m1) {
        int j = 64 + __builtin_ctzll(m1); m1 &= m1 - 1;
        const float* trow = tbl + rts[j] * NA37 + 3;
        float mj  = mm[j];
        float rej = reb[(size_t)j * DIM];
        float s = 0.f;
#pragma unroll
        for (int a = 0; a < NSC; ++a) {
            float vm = trow[a] * mj;
            s += vm * (rej + vm * ae[(a + 3) * DIM + d]);
        }
        r += s;
    }

    // ---- phase 4: epilogue ----
    float m_i = mm[i];
    const float* trowi = tbl + rts[i] * NA37 + 3;
    float red = reb[(size_t)i * DIM];
    float* orow = out + (size_t)bi * NSC * DIM + d;
#pragma unroll
    for (int a = 0; a < NSC; ++a) {
        float vm = trowi[a] * m_i;
        float sc = vm * (red + vm * ae[(a + 3) * DIM + d]);
        orow[(size_t)a * DIM] = (vm > 0.f) ? (r - sc) : 0.f;
    }
}

extern "C" void kernel_launch(void* const* d_in, const int* in_sizes, int n_in,
                              void* d_out, int out_size, void* d_ws, size_t ws_size,
                              hipStream_t stream) {
    const float* aa   = (const float*)d_in[0];
    const float* re   = (const float*)d_in[1];
    const float* bb   = (const float*)d_in[2];
    const float* mask = (const float*)d_in[3];
    const float* tbl  = (const float*)d_in[4];
    const float* ae   = (const float*)d_in[5];
    float* out = (float*)d_out;

    const int BL = in_sizes[3];  // B*L = 256

    k_fused<<<BL, DIM, 0, stream>>>(aa, re, bb, mask, tbl, ae, out);
}